// Round 12
// baseline (463.685 us; speedup 1.0000x reference)
//
#include <hip/hip_runtime.h>
#include <hip/hip_bf16.h>

#define N_NODES 16384
#define FDIM 512

typedef __attribute__((address_space(1))) const void gvoid_t;
typedef __attribute__((address_space(3))) void lvoid_t;
typedef float vfloat4 __attribute__((ext_vector_type(4)));

#define SCHED_FENCE() __builtin_amdgcn_sched_barrier(0)

// ---------------- pipelined row-aggregation GEMM ----------------
// r11 structure with 8-wave blocks (V-L2-traffic probe):
// 512 threads = 8 waves x RPW=4 = 32 rows/block, 512 blocks -> every block
// re-reads V once per pass, so V-L2 traffic halves vs r11 (1 GB -> 0.5 GB);
// if A-streaming was thrashing V out of the per-XCD L2s (hidden HBM re-fetch),
// this halves that too. Occupancy unchanged: 128-reg tier -> 4 waves/SIMD =
// 2 blocks x 8 waves = 16 waves/CU; LDS 2x(2x16KB)=64KB/CU; LDS:A ratio same.
// Everything else proven: KT=256 dbuf, glds w16 (linear dest + pre-swizzled
// src), XOR-swizzled [k][c] tile, counted vmcnt(4) + raw s_barrier, nt A-loads,
// fused epilogues (FUSE 0/1/2).
// vmcnt ledger (2-slot stage + 4-load A): at COMPUTE's first a-use outstanding
// = a_cur 4 + stage 2 + a_next 4 = 10 -> compiler emits vmcnt(6) retiring a_cur;
// explicit vmcnt(4) before barrier retires stage(t+1), keeps a_next flying.
template <int KTOT, int RELU, int HASBIAS, int FUSE>
__global__ __launch_bounds__(512, 2)
void k_rowagg(const float* __restrict__ A,
              const float* __restrict__ V,
              const float* __restrict__ bias,
              float* __restrict__ out,
              const float* __restrict__ w2,
              const float* __restrict__ wd,
              const float* __restrict__ bdp) {
    constexpr int KT = 256;
    constexpr int NT = KTOT / KT;
    constexpr int TB = KT * 16 * 4;        // 16 KB per buffer
    __shared__ char lv[2 * TB];            // 32 KB

    const int tid = threadIdx.x;
    const int lane = tid & 63;
    const int w = tid >> 6;                // 0..7
    const size_t row0 = (size_t)blockIdx.x * 32 + (size_t)w * 4;

    // pre-swizzled global source dword index per staging slot s (2 slots x
    // 512 threads x 16 B = 16 KB): linear LDS dest D = s*8192 + tid*16,
    // logical source byte L = D ^ (((D>>8)&7)<<4)
    int sw_src[2];
#pragma unroll
    for (int s = 0; s < 2; ++s) {
        const int D = s * 8192 + tid * 16;
        sw_src[s] = (D ^ (((D >> 8) & 7) << 4)) >> 2;
    }

    unsigned zoff = 0;  // always 0; opaque to the compiler after each barrier

    auto STAGE = [&](int halfoff, int t) {
        const float* vt = V + (size_t)t * (KT * 16);
#pragma unroll
        for (int s = 0; s < 2; ++s) {
            __builtin_amdgcn_global_load_lds(
                (gvoid_t*)(const void*)(vt + sw_src[s]),
                (lvoid_t*)(void*)(lv + zoff + halfoff + s * 8192 + tid * 16),
                16, 0, 0);
        }
    };

    auto LOADA = [&](vfloat4 (&a)[4], int t) {
#pragma unroll
        for (int r = 0; r < 4; ++r)
            a[r] = __builtin_nontemporal_load(
                reinterpret_cast<const vfloat4*>(
                    A + (row0 + r) * (size_t)KTOT + (size_t)t * KT + lane * 4));
    };

    float acc[4][16];
#pragma unroll
    for (int r = 0; r < 4; ++r)
#pragma unroll
        for (int c = 0; c < 16; ++c) acc[r][c] = 0.f;

    auto COMPUTE = [&](const vfloat4 (&a)[4], unsigned roff) {
#pragma unroll
        for (int kk = 0; kk < 4; ++kk) {
            vfloat4 vv[4];
#pragma unroll
            for (int cc = 0; cc < 4; ++cc) {
                const unsigned B = (unsigned)lane * 256u + ((unsigned)kk << 6) +
                                   ((unsigned)cc << 4);
                const unsigned P = B ^ (((unsigned)lane & 7u) << 4);
                vv[cc] = *reinterpret_cast<const vfloat4*>(lv + roff + P);
            }
#pragma unroll
            for (int cc = 0; cc < 4; ++cc) {
#pragma unroll
                for (int r = 0; r < 4; ++r) {
                    const float ak = a[r][kk];
                    acc[r][cc * 4 + 0] += ak * vv[cc][0];
                    acc[r][cc * 4 + 1] += ak * vv[cc][1];
                    acc[r][cc * 4 + 2] += ak * vv[cc][2];
                    acc[r][cc * 4 + 3] += ak * vv[cc][3];
                }
            }
        }
    };

    vfloat4 a0[4], a1[4];

    // prologue: stage tile 0 -> buf0 (2 glds), prefetch A(0) (4 loads);
    // vmcnt(4) retires the stage, keeps a0 in flight; barrier syncs.
    STAGE(0, 0);
    SCHED_FENCE();
    LOADA(a0, 0);
    SCHED_FENCE();
    asm volatile("s_waitcnt vmcnt(4)" ::: "memory");
    __builtin_amdgcn_s_barrier();
    asm volatile("" : "+v"(zoff));
    SCHED_FENCE();

#pragma unroll 1
    for (int t = 0; t < NT; t += 2) {
        STAGE(TB, t + 1);
        SCHED_FENCE();
        LOADA(a1, t + 1);
        SCHED_FENCE();
        COMPUTE(a0, zoff + 0);
        SCHED_FENCE();
        asm volatile("s_waitcnt vmcnt(4)" ::: "memory");
        __builtin_amdgcn_s_barrier();
        asm volatile("" : "+v"(zoff));
        SCHED_FENCE();

        if (t + 2 < NT) {
            STAGE(0, t + 2);
            SCHED_FENCE();
            LOADA(a0, t + 2);
            SCHED_FENCE();
            COMPUTE(a1, zoff + TB);
            SCHED_FENCE();
            asm volatile("s_waitcnt vmcnt(4)" ::: "memory");
            __builtin_amdgcn_s_barrier();
            asm volatile("" : "+v"(zoff));
            SCHED_FENCE();
        } else {
            COMPUTE(a1, zoff + TB);
        }
    }

    // butterfly-reduce the 64 (r,c) partials; lane v=r*16+c keeps value v.
    float o = 0.f;
#pragma unroll
    for (int r = 0; r < 4; ++r) {
#pragma unroll
        for (int c = 0; c < 16; ++c) {
            float s = acc[r][c];
            s += __shfl_xor(s, 1);  s += __shfl_xor(s, 2);  s += __shfl_xor(s, 4);
            s += __shfl_xor(s, 8);  s += __shfl_xor(s, 16); s += __shfl_xor(s, 32);
            o = (r * 16 + c == lane) ? s : o;
        }
    }
    if (HASBIAS) o += bias[lane & 15];
    if (RELU) o = fmaxf(o, 0.f);

    if (FUSE == 0) {
        out[row0 * 16 + lane] = o;
    } else if (FUSE == 1) {
        // hw[row][c] = sum_k h[row][k] * W2[k][c]; h[row][k] in lane (lane&48)|k
        const int c = lane & 15;
        float s = 0.f;
#pragma unroll
        for (int k = 0; k < 16; ++k) {
            const float hk = __shfl(o, (lane & 48) + k);
            s += hk * w2[k * 16 + c];
        }
        out[row0 * 16 + lane] = s;
    } else {
        // softmax over the 16-lane class group, dot Wd, + bd -> scalar per row
        const int c = lane & 15;
        float m = o;
        m = fmaxf(m, __shfl_xor(m, 1));
        m = fmaxf(m, __shfl_xor(m, 2));
        m = fmaxf(m, __shfl_xor(m, 4));
        m = fmaxf(m, __shfl_xor(m, 8));
        const float e = expf(o - m);
        float se = e, sd = e * wd[c];
        se += __shfl_xor(se, 1); sd += __shfl_xor(sd, 1);
        se += __shfl_xor(se, 2); sd += __shfl_xor(sd, 2);
        se += __shfl_xor(se, 4); sd += __shfl_xor(sd, 4);
        se += __shfl_xor(se, 8); sd += __shfl_xor(sd, 8);
        if (c == 0) out[row0 + (lane >> 4)] = sd / se + bdp[0];
    }
}

extern "C" void kernel_launch(void* const* d_in, const int* in_sizes, int n_in,
                              void* d_out, int out_size, void* d_ws, size_t ws_size,
                              hipStream_t stream) {
    const float* x  = (const float*)d_in[0];
    const float* A  = (const float*)d_in[1];
    const float* W1 = (const float*)d_in[2];
    const float* b1 = (const float*)d_in[3];
    const float* W2 = (const float*)d_in[4];
    const float* b2 = (const float*)d_in[5];
    const float* Wd = (const float*)d_in[6];
    const float* bd = (const float*)d_in[7];
    float* out = (float*)d_out;

    float* ws = (float*)d_ws;
    float* xw = ws;                        // [N,16] 1 MB
    float* hw = ws + 1 * N_NODES * 16;     // [N,16] 1 MB

    // xw = x @ W1
    k_rowagg<FDIM, 0, 0, 0><<<N_NODES / 32, 512, 0, stream>>>(
        x, W1, b1, xw, nullptr, nullptr, nullptr);
    // hw = relu(A @ xw + b1) @ W2    (pass 1, fused k3)
    k_rowagg<N_NODES, 1, 1, 1><<<N_NODES / 32, 512, 0, stream>>>(
        A, xw, b1, hw, W2, nullptr, nullptr);
    // out = softmax(A @ hw + b2) @ Wd + bd    (pass 2, fused k5)
    k_rowagg<N_NODES, 0, 1, 2><<<N_NODES / 32, 512, 0, stream>>>(
        A, hw, b2, out, nullptr, Wd, bd);
}